// Round 2
// baseline (516.896 us; speedup 1.0000x reference)
//
#include <hip/hip_runtime.h>

using u16 = unsigned short;
typedef __bf16 bf16x8 __attribute__((ext_vector_type(8)));
typedef float f32x4 __attribute__((ext_vector_type(4)));

__device__ __forceinline__ u16 f2bf(float f) {
  unsigned u = __builtin_bit_cast(unsigned, f);
  u += 0x7FFFu + ((u >> 16) & 1u);
  return (u16)(u >> 16);
}

#define GLD_LDS16(g, l)                                                                   \
  __builtin_amdgcn_global_load_lds((const __attribute__((address_space(1))) void*)(g),    \
                                   (__attribute__((address_space(3))) void*)(l), 16, 0, 0)

__global__ void cvt_f32_bf16(const float* __restrict__ in, u16* __restrict__ out, int n4) {
  int i = blockIdx.x * blockDim.x + threadIdx.x;
  const int st = gridDim.x * blockDim.x;
  for (; i < n4; i += st) {
    float4 v = reinterpret_cast<const float4*>(in)[i];
    ushort4 o = make_ushort4(f2bf(v.x), f2bf(v.y), f2bf(v.z), f2bf(v.w));
    reinterpret_cast<ushort4*>(out)[i] = o;
  }
}

// C = A(M x 1024) * Bt(1024 x 1024)^T + bias, bf16 MFMA, 128x128 tile, BK=64.
// EPI: 0 = Q-proj (rope over heads: position = col>>6), bf16 out [m][n]
//      1 = K-proj (rope over time: position = row&2047), bf16 out [m][n]
//      2 = V-proj (no rope), bf16 out transposed per head: vT[((b*16+h)*64+d)*2048 + s]
//      3 = O-proj, fp32 out [m][n]
template <int EPI>
__global__ __launch_bounds__(256, 2) void gemm_bt(const u16* __restrict__ A,
                                                  const u16* __restrict__ Bt,
                                                  const float* __restrict__ bias,
                                                  void* __restrict__ outp) {
  __shared__ u16 lA[128 * 64];
  __shared__ u16 lB[128 * 64];
  const int tid = threadIdx.x;
  const int l = tid & 63;
  const int w = tid >> 6;
  const int wr = w >> 1, wc = w & 1;
  const int l15 = l & 15, lg = l >> 4;
  const int br = blockIdx.x >> 3;  // M/128 = 64 tiles
  const int bc = blockIdx.x & 7;   // N/128 = 8 tiles

  f32x4 acc[4][4];
#pragma unroll
  for (int m = 0; m < 4; ++m)
#pragma unroll
    for (int n = 0; n < 4; ++n) acc[m][n] = f32x4{0.f, 0.f, 0.f, 0.f};

  const int srow = tid >> 3;         // 0..31
  const int scole = (tid & 7) * 8;   // element col within BK
  const u16* Abase = A + (size_t)(br * 128 + srow) * 1024 + scole;
  const u16* Bbase = Bt + (size_t)(bc * 128 + srow) * 1024 + scole;

  for (int kk = 0; kk < 1024; kk += 64) {
#pragma unroll
    for (int i = 0; i < 4; ++i) {
      GLD_LDS16(Abase + (size_t)(i * 32) * 1024 + kk, &lA[i * 2048 + tid * 8]);
      GLD_LDS16(Bbase + (size_t)(i * 32) * 1024 + kk, &lB[i * 2048 + tid * 8]);
    }
    __syncthreads();
#pragma unroll
    for (int ks = 0; ks < 2; ++ks) {
      bf16x8 af[4], bfr[4];
#pragma unroll
      for (int m = 0; m < 4; ++m)
        af[m] = *reinterpret_cast<const bf16x8*>(&lA[(wr * 64 + m * 16 + l15) * 64 + ks * 32 + lg * 8]);
#pragma unroll
      for (int n = 0; n < 4; ++n)
        bfr[n] = *reinterpret_cast<const bf16x8*>(&lB[(wc * 64 + n * 16 + l15) * 64 + ks * 32 + lg * 8]);
#pragma unroll
      for (int m = 0; m < 4; ++m)
#pragma unroll
        for (int n = 0; n < 4; ++n)
          acc[m][n] = __builtin_amdgcn_mfma_f32_16x16x32_bf16(af[m], bfr[n], acc[m][n], 0, 0, 0);
    }
    __syncthreads();
  }

  const int row0 = br * 128 + wr * 64;
  const int col0 = bc * 128 + wc * 64;

  if constexpr (EPI == 0 || EPI == 1) {
    u16* out = reinterpret_cast<u16*>(outp);
#pragma unroll
    for (int n = 0; n < 4; ++n) {
      const int gn = col0 + n * 16 + l15;
      const float bv = bias[gn];
      const int p = (gn & 63) >> 1;
      const float invf = __expf((float)p * -0.28782313663f);  // 10000^(-p/32)
      float ss = 0.f, cc = 0.f;
      if constexpr (EPI == 0) {
        const float th = (float)(gn >> 6) * invf;  // position = head index
        sincosf(th, &ss, &cc);
      }
#pragma unroll
      for (int m = 0; m < 4; ++m) {
        const int gm0 = row0 + m * 16 + lg * 4;
#pragma unroll
        for (int r = 0; r < 4; ++r) {
          float x = acc[m][n][r] + bv;
          if constexpr (EPI == 1) {
            const float th = (float)((gm0 + r) & 2047) * invf;  // position = time
            sincosf(th, &ss, &cc);
          }
          const float xp = __shfl_xor(x, 1);  // partner column (adjacent lane)
          const float o = (gn & 1) ? fmaf(xp, ss, x * cc) : fmaf(-xp, ss, x * cc);
          out[(size_t)(gm0 + r) * 1024 + gn] = f2bf(o);
        }
      }
    }
  } else if constexpr (EPI == 2) {
    u16* vT = reinterpret_cast<u16*>(outp);
#pragma unroll
    for (int n = 0; n < 4; ++n) {
      const int gn = col0 + n * 16 + l15;
      const float bv = bias[gn];
      const int hh = gn >> 6, dd = gn & 63;
#pragma unroll
      for (int m = 0; m < 4; ++m) {
        const int gm0 = row0 + m * 16 + lg * 4;
        const int bb = gm0 >> 11, s0 = gm0 & 2047;
        ushort4 pk = make_ushort4(f2bf(acc[m][n][0] + bv), f2bf(acc[m][n][1] + bv),
                                  f2bf(acc[m][n][2] + bv), f2bf(acc[m][n][3] + bv));
        *reinterpret_cast<ushort4*>(vT + ((size_t)((bb * 16 + hh) * 64 + dd) * 2048 + s0)) = pk;
      }
    }
  } else {
    float* out = reinterpret_cast<float*>(outp);
#pragma unroll
    for (int n = 0; n < 4; ++n) {
      const int gn = col0 + n * 16 + l15;
      const float bv = bias[gn];
#pragma unroll
      for (int m = 0; m < 4; ++m) {
        const int gm0 = row0 + m * 16 + lg * 4;
#pragma unroll
        for (int r = 0; r < 4; ++r) out[(size_t)(gm0 + r) * 1024 + gn] = acc[m][n][r] + bv;
      }
    }
  }
}

// Flash attention: block = (bh, q-tile of 64 rows), 4 waves x 16 q-rows each.
// Q [m][n] bf16, K [m][n] bf16, Vt [(bh*64+d)*2048 + s] bf16. Scale = 1/32.
__global__ __launch_bounds__(256, 2) void attn_fwd(const u16* __restrict__ Q,
                                                   const u16* __restrict__ K,
                                                   const u16* __restrict__ Vt,
                                                   u16* __restrict__ ctx) {
  __shared__ u16 sK[64 * 64];
  __shared__ u16 sV[64 * 64];          // Vt tile: [d][kv]
  __shared__ __bf16 sP[4][16 * 72];    // per-wave P, padded row stride 72
  const int tid = threadIdx.x;
  const int l = tid & 63, w = tid >> 6;
  const int l15 = l & 15, lg = l >> 4;
  const int qt = blockIdx.x & 31, bh = blockIdx.x >> 5;
  const int b = bh >> 4, h = bh & 15;

  bf16x8 qf0, qf1;
  {
    const u16* qp = Q + (size_t)(b * 2048 + qt * 64 + w * 16 + l15) * 1024 + h * 64 + lg * 8;
    qf0 = *reinterpret_cast<const bf16x8*>(qp);
    qf1 = *reinterpret_cast<const bf16x8*>(qp + 32);
  }

  float m_i[4], l_i[4];
  f32x4 acc_o[4];
#pragma unroll
  for (int r = 0; r < 4; ++r) { m_i[r] = -1e30f; l_i[r] = 0.f; }
#pragma unroll
  for (int n = 0; n < 4; ++n) acc_o[n] = f32x4{0.f, 0.f, 0.f, 0.f};

  const int srow = tid >> 3, scole = (tid & 7) * 8;
  const u16* Kbase = K + (size_t)(b * 2048 + srow) * 1024 + h * 64 + scole;
  const u16* Vbase = Vt + (size_t)(bh * 64 + srow) * 2048 + scole;

  for (int j = 0; j < 32; ++j) {
    __syncthreads();
#pragma unroll
    for (int i = 0; i < 2; ++i) {
      GLD_LDS16(Kbase + (size_t)(j * 64 + i * 32) * 1024, &sK[i * 2048 + tid * 8]);
      GLD_LDS16(Vbase + (size_t)(i * 32) * 2048 + j * 64, &sV[i * 2048 + tid * 8]);
    }
    __syncthreads();

    f32x4 accs[4];
#pragma unroll
    for (int nk = 0; nk < 4; ++nk) accs[nk] = f32x4{0.f, 0.f, 0.f, 0.f};
#pragma unroll
    for (int nk = 0; nk < 4; ++nk) {
      bf16x8 kf0 = *reinterpret_cast<const bf16x8*>(&sK[(nk * 16 + l15) * 64 + lg * 8]);
      bf16x8 kf1 = *reinterpret_cast<const bf16x8*>(&sK[(nk * 16 + l15) * 64 + 32 + lg * 8]);
      accs[nk] = __builtin_amdgcn_mfma_f32_16x16x32_bf16(qf0, kf0, accs[nk], 0, 0, 0);
      accs[nk] = __builtin_amdgcn_mfma_f32_16x16x32_bf16(qf1, kf1, accs[nk], 0, 0, 0);
    }

    float mr[4], corr[4], rs[4];
#pragma unroll
    for (int nk = 0; nk < 4; ++nk)
#pragma unroll
      for (int r = 0; r < 4; ++r) accs[nk][r] *= 0.03125f;  // 1/sqrt(1024)
#pragma unroll
    for (int r = 0; r < 4; ++r)
      mr[r] = fmaxf(fmaxf(accs[0][r], accs[1][r]), fmaxf(accs[2][r], accs[3][r]));
#pragma unroll
    for (int off = 1; off <= 8; off <<= 1)
#pragma unroll
      for (int r = 0; r < 4; ++r) mr[r] = fmaxf(mr[r], __shfl_xor(mr[r], off));
#pragma unroll
    for (int r = 0; r < 4; ++r) {
      const float mn = fmaxf(m_i[r], mr[r]);
      corr[r] = __expf(m_i[r] - mn);
      m_i[r] = mn;
    }
#pragma unroll
    for (int nk = 0; nk < 4; ++nk)
#pragma unroll
      for (int r = 0; r < 4; ++r) accs[nk][r] = __expf(accs[nk][r] - m_i[r]);
#pragma unroll
    for (int r = 0; r < 4; ++r) rs[r] = (accs[0][r] + accs[1][r]) + (accs[2][r] + accs[3][r]);
#pragma unroll
    for (int off = 1; off <= 8; off <<= 1)
#pragma unroll
      for (int r = 0; r < 4; ++r) rs[r] += __shfl_xor(rs[r], off);
#pragma unroll
    for (int r = 0; r < 4; ++r) l_i[r] = l_i[r] * corr[r] + rs[r];
#pragma unroll
    for (int n = 0; n < 4; ++n)
#pragma unroll
      for (int r = 0; r < 4; ++r) acc_o[n][r] *= corr[r];

    // P -> LDS (wave-private), then read back as MFMA A-operand
    __bf16* sPw = &sP[w][0];
#pragma unroll
    for (int nk = 0; nk < 4; ++nk)
#pragma unroll
      for (int r = 0; r < 4; ++r)
        sPw[(lg * 4 + r) * 72 + nk * 16 + l15] = (__bf16)accs[nk][r];
    __threadfence_block();  // order same-wave LDS write -> vector read

#pragma unroll
    for (int ks = 0; ks < 2; ++ks) {
      bf16x8 pa = *reinterpret_cast<const bf16x8*>(&sPw[l15 * 72 + ks * 32 + lg * 8]);
#pragma unroll
      for (int n = 0; n < 4; ++n) {
        bf16x8 vf = *reinterpret_cast<const bf16x8*>(&sV[(n * 16 + l15) * 64 + ks * 32 + lg * 8]);
        acc_o[n] = __builtin_amdgcn_mfma_f32_16x16x32_bf16(pa, vf, acc_o[n], 0, 0, 0);
      }
    }
  }

#pragma unroll
  for (int r = 0; r < 4; ++r) l_i[r] = 1.f / l_i[r];
  u16* obase = ctx + (size_t)(b * 2048 + qt * 64 + w * 16) * 1024 + h * 64;
#pragma unroll
  for (int n = 0; n < 4; ++n)
#pragma unroll
    for (int r = 0; r < 4; ++r)
      obase[(size_t)(lg * 4 + r) * 1024 + n * 16 + l15] = f2bf(acc_o[n][r] * l_i[r]);
}

extern "C" void kernel_launch(void* const* d_in, const int* in_sizes, int n_in, void* d_out,
                              int out_size, void* d_ws, size_t ws_size, hipStream_t stream) {
  (void)in_sizes; (void)n_in; (void)out_size; (void)ws_size;
  const float* query = (const float*)d_in[0];
  const float* key = (const float*)d_in[1];
  const float* value = (const float*)d_in[2];
  const float* Wq = (const float*)d_in[3];
  const float* bq = (const float*)d_in[4];
  const float* Wk = (const float*)d_in[5];
  const float* bk = (const float*)d_in[6];
  const float* Wv = (const float*)d_in[7];
  const float* bv = (const float*)d_in[8];
  const float* Wo = (const float*)d_in[9];
  const float* bo = (const float*)d_in[10];

  char* ws = (char*)d_ws;
  const size_t MB = (size_t)1 << 20;
  u16* xq = (u16*)(ws + 0 * MB);    // 16 MiB each: bf16 casts of inputs
  u16* xk = (u16*)(ws + 16 * MB);
  u16* xv = (u16*)(ws + 32 * MB);
  u16* wqb = (u16*)(ws + 48 * MB);  // 2 MiB each: bf16 weights
  u16* wkb = (u16*)(ws + 50 * MB);
  u16* wvb = (u16*)(ws + 52 * MB);
  u16* wob = (u16*)(ws + 54 * MB);
  u16* qb = (u16*)(ws + 56 * MB);   // 16 MiB: q post-proj+rope, [m][n]
  u16* kb = (u16*)(ws + 72 * MB);   // 16 MiB: k post-proj+rope, [m][n]
  u16* vT = (u16*)(ws + 88 * MB);   // 16 MiB: v transposed per head [bh][d][s]
  u16* cx = (u16*)(ws + 104 * MB);  // 16 MiB: attention output [m][n]

  cvt_f32_bf16<<<2048, 256, 0, stream>>>(query, xq, 2097152);
  cvt_f32_bf16<<<2048, 256, 0, stream>>>(key, xk, 2097152);
  cvt_f32_bf16<<<2048, 256, 0, stream>>>(value, xv, 2097152);
  cvt_f32_bf16<<<256, 256, 0, stream>>>(Wq, wqb, 262144);
  cvt_f32_bf16<<<256, 256, 0, stream>>>(Wk, wkb, 262144);
  cvt_f32_bf16<<<256, 256, 0, stream>>>(Wv, wvb, 262144);
  cvt_f32_bf16<<<256, 256, 0, stream>>>(Wo, wob, 262144);

  gemm_bt<0><<<512, 256, 0, stream>>>(xq, wqb, bq, qb);
  gemm_bt<1><<<512, 256, 0, stream>>>(xk, wkb, bk, kb);
  gemm_bt<2><<<512, 256, 0, stream>>>(xv, wvb, bv, vT);
  attn_fwd<<<2048, 256, 0, stream>>>(qb, kb, vT, cx);
  gemm_bt<3><<<512, 256, 0, stream>>>(cx, wob, bo, d_out);
}

// Round 3
// 437.545 us; speedup vs baseline: 1.1814x; 1.1814x over previous
//
#include <hip/hip_runtime.h>

using u16 = unsigned short;
typedef __bf16 bf16x8 __attribute__((ext_vector_type(8)));
typedef float f32x4 __attribute__((ext_vector_type(4)));

__device__ __forceinline__ u16 f2bf(float f) {
  unsigned u = __builtin_bit_cast(unsigned, f);
  u += 0x7FFFu + ((u >> 16) & 1u);
  return (u16)(u >> 16);
}

#define GLD_LDS16(g, l)                                                                   \
  __builtin_amdgcn_global_load_lds((const __attribute__((address_space(1))) void*)(g),    \
                                   (__attribute__((address_space(3))) void*)(l), 16, 0, 0)

// Convert up to 4 fp32 tensors to bf16 in one launch. Blocks [t<<LOG2NB, (t+1)<<LOG2NB)
// handle tensor t; n4 = float4 count per tensor (all equal).
template <int LOG2NB>
__global__ void cvt_multi(const float* __restrict__ i0, const float* __restrict__ i1,
                          const float* __restrict__ i2, const float* __restrict__ i3,
                          u16* __restrict__ o0, u16* __restrict__ o1, u16* __restrict__ o2,
                          u16* __restrict__ o3, int n4) {
  const int which = blockIdx.x >> LOG2NB;
  const float* in = which == 0 ? i0 : which == 1 ? i1 : which == 2 ? i2 : i3;
  u16* out = which == 0 ? o0 : which == 1 ? o1 : which == 2 ? o2 : o3;
  int i = (blockIdx.x & ((1 << LOG2NB) - 1)) * blockDim.x + threadIdx.x;
  const int st = (1 << LOG2NB) * blockDim.x;
  for (; i < n4; i += st) {
    float4 v = reinterpret_cast<const float4*>(in)[i];
    ushort4 o = make_ushort4(f2bf(v.x), f2bf(v.y), f2bf(v.z), f2bf(v.w));
    reinterpret_cast<ushort4*>(out)[i] = o;
  }
}

// C = A(M x 1024) * Bt(1024 x 1024)^T + bias, bf16 MFMA, 128x128 tile, BK=64.
// Double-buffered LDS (2-phase prefetch) + XOR bank-swizzle (linear LDS dest,
// pre-swizzled global source column, matching XOR on ds_read).
// EPI: 0 = Q-proj (rope over heads), 1 = K-proj (rope over time),
//      2 = V-proj -> vT[((b*16+h)*64+d)*2048+s], 3 = O-proj fp32 out.
template <int EPI>
__global__ __launch_bounds__(256, 2) void gemm_bt(const u16* __restrict__ A,
                                                  const u16* __restrict__ Bt,
                                                  const float* __restrict__ bias,
                                                  void* __restrict__ outp) {
  __shared__ u16 lA[2][128 * 64];
  __shared__ u16 lB[2][128 * 64];
  const int tid = threadIdx.x;
  const int l = tid & 63;
  const int w = tid >> 6;
  const int wr = w >> 1, wc = w & 1;
  const int l15 = l & 15, lg = l >> 4;
  const int swz = (l15 & 7) << 3;  // element-XOR for ds_read side
  const int br = blockIdx.x >> 3;
  const int bc = blockIdx.x & 7;

  f32x4 acc[4][4];
#pragma unroll
  for (int m = 0; m < 4; ++m)
#pragma unroll
    for (int n = 0; n < 4; ++n) acc[m][n] = f32x4{0.f, 0.f, 0.f, 0.f};

  const int srow = tid >> 3;                           // 0..31
  const int scol = ((tid & 7) ^ (srow & 7)) * 8;       // pre-swizzled source chunk
  const u16* Abase = A + (size_t)(br * 128 + srow) * 1024 + scol;
  const u16* Bbase = Bt + (size_t)(bc * 128 + srow) * 1024 + scol;

  auto stage = [&](int buf, int kk) {
#pragma unroll
    for (int i = 0; i < 4; ++i) {
      GLD_LDS16(Abase + (size_t)(i * 32) * 1024 + kk, &lA[buf][i * 2048 + tid * 8]);
      GLD_LDS16(Bbase + (size_t)(i * 32) * 1024 + kk, &lB[buf][i * 2048 + tid * 8]);
    }
  };

  stage(0, 0);
  __syncthreads();

  for (int it = 0; it < 16; ++it) {
    const int cur = it & 1;
    if (it < 15) stage(cur ^ 1, (it + 1) * 64);
#pragma unroll
    for (int ks = 0; ks < 2; ++ks) {
      const int c = (ks * 32 + lg * 8) ^ swz;
      bf16x8 af[4], bfr[4];
#pragma unroll
      for (int m = 0; m < 4; ++m)
        af[m] = *reinterpret_cast<const bf16x8*>(&lA[cur][(wr * 64 + m * 16 + l15) * 64 + c]);
#pragma unroll
      for (int n = 0; n < 4; ++n)
        bfr[n] = *reinterpret_cast<const bf16x8*>(&lB[cur][(wc * 64 + n * 16 + l15) * 64 + c]);
#pragma unroll
      for (int m = 0; m < 4; ++m)
#pragma unroll
        for (int n = 0; n < 4; ++n)
          acc[m][n] = __builtin_amdgcn_mfma_f32_16x16x32_bf16(af[m], bfr[n], acc[m][n], 0, 0, 0);
    }
    __syncthreads();
  }

  const int row0 = br * 128 + wr * 64;
  const int col0 = bc * 128 + wc * 64;

  if constexpr (EPI == 0 || EPI == 1) {
    u16* out = reinterpret_cast<u16*>(outp);
#pragma unroll
    for (int n = 0; n < 4; ++n) {
      const int gn = col0 + n * 16 + l15;
      const float bv = bias[gn];
      const int p = (gn & 63) >> 1;
      const float invf = __expf((float)p * -0.28782313663f);  // 10000^(-p/32)
      float ss = 0.f, cc = 0.f;
      if constexpr (EPI == 0) {
        const float th = (float)(gn >> 6) * invf;  // position = head index
        sincosf(th, &ss, &cc);
      }
#pragma unroll
      for (int m = 0; m < 4; ++m) {
        const int gm0 = row0 + m * 16 + lg * 4;
#pragma unroll
        for (int r = 0; r < 4; ++r) {
          float x = acc[m][n][r] + bv;
          if constexpr (EPI == 1) {
            const float th = (float)((gm0 + r) & 2047) * invf;  // position = time
            sincosf(th, &ss, &cc);
          }
          const float xp = __shfl_xor(x, 1);  // partner column (adjacent lane)
          const float o = (gn & 1) ? fmaf(xp, ss, x * cc) : fmaf(-xp, ss, x * cc);
          out[(size_t)(gm0 + r) * 1024 + gn] = f2bf(o);
        }
      }
    }
  } else if constexpr (EPI == 2) {
    u16* vT = reinterpret_cast<u16*>(outp);
#pragma unroll
    for (int n = 0; n < 4; ++n) {
      const int gn = col0 + n * 16 + l15;
      const float bv = bias[gn];
      const int hh = gn >> 6, dd = gn & 63;
#pragma unroll
      for (int m = 0; m < 4; ++m) {
        const int gm0 = row0 + m * 16 + lg * 4;
        const int bb = gm0 >> 11, s0 = gm0 & 2047;
        ushort4 pk = make_ushort4(f2bf(acc[m][n][0] + bv), f2bf(acc[m][n][1] + bv),
                                  f2bf(acc[m][n][2] + bv), f2bf(acc[m][n][3] + bv));
        *reinterpret_cast<ushort4*>(vT + ((size_t)((bb * 16 + hh) * 64 + dd) * 2048 + s0)) = pk;
      }
    }
  } else {
    float* out = reinterpret_cast<float*>(outp);
#pragma unroll
    for (int n = 0; n < 4; ++n) {
      const int gn = col0 + n * 16 + l15;
      const float bv = bias[gn];
#pragma unroll
      for (int m = 0; m < 4; ++m) {
        const int gm0 = row0 + m * 16 + lg * 4;
#pragma unroll
        for (int r = 0; r < 4; ++r) out[(size_t)(gm0 + r) * 1024 + gn] = acc[m][n][r] + bv;
      }
    }
  }
}

// Flash attention: block = (bh, q-tile of 64 rows), 4 waves x 16 q-rows each.
// Double-buffered K/V staging + XOR bank-swizzle. Scale = 1/32.
__global__ __launch_bounds__(256, 2) void attn_fwd(const u16* __restrict__ Q,
                                                   const u16* __restrict__ K,
                                                   const u16* __restrict__ Vt,
                                                   u16* __restrict__ ctx) {
  __shared__ u16 sK[2][64 * 64];
  __shared__ u16 sV[2][64 * 64];       // Vt tile: [d][kv]
  __shared__ __bf16 sP[4][16 * 72];    // per-wave P, padded row stride 72
  const int tid = threadIdx.x;
  const int l = tid & 63, w = tid >> 6;
  const int l15 = l & 15, lg = l >> 4;
  const int swz = (l15 & 7) << 3;
  const int qt = blockIdx.x & 31, bh = blockIdx.x >> 5;
  const int b = bh >> 4, h = bh & 15;

  bf16x8 qf0, qf1;
  {
    const u16* qp = Q + (size_t)(b * 2048 + qt * 64 + w * 16 + l15) * 1024 + h * 64 + lg * 8;
    qf0 = *reinterpret_cast<const bf16x8*>(qp);
    qf1 = *reinterpret_cast<const bf16x8*>(qp + 32);
  }

  float m_i[4], l_i[4];
  f32x4 acc_o[4];
#pragma unroll
  for (int r = 0; r < 4; ++r) { m_i[r] = -1e30f; l_i[r] = 0.f; }
#pragma unroll
  for (int n = 0; n < 4; ++n) acc_o[n] = f32x4{0.f, 0.f, 0.f, 0.f};

  const int srow = tid >> 3;
  const int scol = ((tid & 7) ^ (srow & 7)) * 8;  // pre-swizzled source chunk
  const u16* Kbase = K + (size_t)(b * 2048 + srow) * 1024 + h * 64 + scol;
  const u16* Vbase = Vt + (size_t)(bh * 64 + srow) * 2048 + scol;

  auto stage = [&](int buf, int j) {
#pragma unroll
    for (int i = 0; i < 2; ++i) {
      GLD_LDS16(Kbase + (size_t)(j * 64 + i * 32) * 1024, &sK[buf][i * 2048 + tid * 8]);
      GLD_LDS16(Vbase + (size_t)(i * 32) * 2048 + j * 64, &sV[buf][i * 2048 + tid * 8]);
    }
  };

  stage(0, 0);
  __syncthreads();

  for (int j = 0; j < 32; ++j) {
    const int cur = j & 1;
    if (j < 31) stage(cur ^ 1, j + 1);

    f32x4 accs[4];
#pragma unroll
    for (int nk = 0; nk < 4; ++nk) accs[nk] = f32x4{0.f, 0.f, 0.f, 0.f};
    const int c0 = (lg * 8) ^ swz;
#pragma unroll
    for (int nk = 0; nk < 4; ++nk) {
      bf16x8 kf0 = *reinterpret_cast<const bf16x8*>(&sK[cur][(nk * 16 + l15) * 64 + c0]);
      bf16x8 kf1 = *reinterpret_cast<const bf16x8*>(&sK[cur][(nk * 16 + l15) * 64 + (c0 ^ 32)]);
      accs[nk] = __builtin_amdgcn_mfma_f32_16x16x32_bf16(qf0, kf0, accs[nk], 0, 0, 0);
      accs[nk] = __builtin_amdgcn_mfma_f32_16x16x32_bf16(qf1, kf1, accs[nk], 0, 0, 0);
    }

    float mr[4], corr[4], rs[4];
#pragma unroll
    for (int nk = 0; nk < 4; ++nk)
#pragma unroll
      for (int r = 0; r < 4; ++r) accs[nk][r] *= 0.03125f;  // 1/sqrt(1024)
#pragma unroll
    for (int r = 0; r < 4; ++r)
      mr[r] = fmaxf(fmaxf(accs[0][r], accs[1][r]), fmaxf(accs[2][r], accs[3][r]));
#pragma unroll
    for (int off = 1; off <= 8; off <<= 1)
#pragma unroll
      for (int r = 0; r < 4; ++r) mr[r] = fmaxf(mr[r], __shfl_xor(mr[r], off));
#pragma unroll
    for (int r = 0; r < 4; ++r) {
      const float mn = fmaxf(m_i[r], mr[r]);
      corr[r] = __expf(m_i[r] - mn);
      m_i[r] = mn;
    }
#pragma unroll
    for (int nk = 0; nk < 4; ++nk)
#pragma unroll
      for (int r = 0; r < 4; ++r) accs[nk][r] = __expf(accs[nk][r] - m_i[r]);
#pragma unroll
    for (int r = 0; r < 4; ++r) rs[r] = (accs[0][r] + accs[1][r]) + (accs[2][r] + accs[3][r]);
#pragma unroll
    for (int off = 1; off <= 8; off <<= 1)
#pragma unroll
      for (int r = 0; r < 4; ++r) rs[r] += __shfl_xor(rs[r], off);
#pragma unroll
    for (int r = 0; r < 4; ++r) l_i[r] = l_i[r] * corr[r] + rs[r];
#pragma unroll
    for (int n = 0; n < 4; ++n)
#pragma unroll
      for (int r = 0; r < 4; ++r) acc_o[n][r] *= corr[r];

    // P -> LDS (wave-private), then read back as MFMA A-operand
    __bf16* sPw = &sP[w][0];
#pragma unroll
    for (int nk = 0; nk < 4; ++nk)
#pragma unroll
      for (int r = 0; r < 4; ++r)
        sPw[(lg * 4 + r) * 72 + nk * 16 + l15] = (__bf16)accs[nk][r];
    __threadfence_block();  // order same-wave LDS write -> vector read

#pragma unroll
    for (int ks = 0; ks < 2; ++ks) {
      bf16x8 pa = *reinterpret_cast<const bf16x8*>(&sPw[l15 * 72 + ks * 32 + lg * 8]);
#pragma unroll
      for (int n = 0; n < 4; ++n) {
        bf16x8 vf = *reinterpret_cast<const bf16x8*>(
            &sV[cur][(n * 16 + l15) * 64 + ((ks * 32 + lg * 8) ^ swz)]);
        acc_o[n] = __builtin_amdgcn_mfma_f32_16x16x32_bf16(pa, vf, acc_o[n], 0, 0, 0);
      }
    }
    __syncthreads();
  }

#pragma unroll
  for (int r = 0; r < 4; ++r) l_i[r] = 1.f / l_i[r];
  u16* obase = ctx + (size_t)(b * 2048 + qt * 64 + w * 16) * 1024 + h * 64;
#pragma unroll
  for (int n = 0; n < 4; ++n)
#pragma unroll
    for (int r = 0; r < 4; ++r)
      obase[(size_t)(lg * 4 + r) * 1024 + n * 16 + l15] = f2bf(acc_o[n][r] * l_i[r]);
}

extern "C" void kernel_launch(void* const* d_in, const int* in_sizes, int n_in, void* d_out,
                              int out_size, void* d_ws, size_t ws_size, hipStream_t stream) {
  (void)in_sizes; (void)n_in; (void)out_size; (void)ws_size;
  const float* query = (const float*)d_in[0];
  const float* key = (const float*)d_in[1];
  const float* value = (const float*)d_in[2];
  const float* Wq = (const float*)d_in[3];
  const float* bq = (const float*)d_in[4];
  const float* Wk = (const float*)d_in[5];
  const float* bk = (const float*)d_in[6];
  const float* Wv = (const float*)d_in[7];
  const float* bv = (const float*)d_in[8];
  const float* Wo = (const float*)d_in[9];
  const float* bo = (const float*)d_in[10];

  char* ws = (char*)d_ws;
  const size_t MB = (size_t)1 << 20;
  u16* xq = (u16*)(ws + 0 * MB);    // 16 MiB each: bf16 casts of inputs
  u16* xk = (u16*)(ws + 16 * MB);
  u16* xv = (u16*)(ws + 32 * MB);
  u16* wqb = (u16*)(ws + 48 * MB);  // 2 MiB each: bf16 weights
  u16* wkb = (u16*)(ws + 50 * MB);
  u16* wvb = (u16*)(ws + 52 * MB);
  u16* wob = (u16*)(ws + 54 * MB);
  u16* qb = (u16*)(ws + 56 * MB);   // 16 MiB: q post-proj+rope, [m][n]
  u16* kb = (u16*)(ws + 72 * MB);   // 16 MiB: k post-proj+rope, [m][n]
  u16* vT = (u16*)(ws + 88 * MB);   // 16 MiB: v transposed per head [bh][d][s]
  u16* cx = (u16*)(ws + 104 * MB);  // 16 MiB: attention output [m][n]

  // q,k,v in one launch (512 blocks each); weights in one launch (64 blocks each)
  cvt_multi<9><<<1536, 256, 0, stream>>>(query, key, value, query, xq, xk, xv, xq, 2097152);
  cvt_multi<6><<<256, 256, 0, stream>>>(Wq, Wk, Wv, Wo, wqb, wkb, wvb, wob, 262144);

  gemm_bt<0><<<512, 256, 0, stream>>>(xq, wqb, bq, qb);
  gemm_bt<1><<<512, 256, 0, stream>>>(xk, wkb, bk, kb);
  gemm_bt<2><<<512, 256, 0, stream>>>(xv, wvb, bv, vT);
  attn_fwd<<<2048, 256, 0, stream>>>(qb, kb, vT, cx);
  gemm_bt<3><<<512, 256, 0, stream>>>(cx, wob, bo, d_out);
}